// Round 3
// baseline (2304.576 us; speedup 1.0000x reference)
//
#include <hip/hip_runtime.h>
#include <stdint.h>
#include <math.h>

#define NB 16384      // batch
#define NSEQ 32       // sequence length
#define NV 1001       // vocab (V+1)
#define NROWS 32768   // 2 * NB flattened rows

// ---------------- threefry2x32 (JAX-exact) ----------------
__device__ __forceinline__ void tf2x32(uint32_t k0, uint32_t k1,
                                       uint32_t x0, uint32_t x1,
                                       uint32_t& o0, uint32_t& o1) {
  const uint32_t ks0 = k0, ks1 = k1, ks2 = k0 ^ k1 ^ 0x1BD11BDAu;
  x0 += ks0; x1 += ks1;
  const int rA[4] = {13, 15, 26, 6};
  const int rB[4] = {17, 29, 16, 24};
#pragma unroll
  for (int i = 0; i < 4; ++i) { x0 += x1; x1 = (x1 << rA[i]) | (x1 >> (32 - rA[i])); x1 ^= x0; }
  x0 += ks1; x1 += ks2 + 1u;
#pragma unroll
  for (int i = 0; i < 4; ++i) { x0 += x1; x1 = (x1 << rB[i]) | (x1 >> (32 - rB[i])); x1 ^= x0; }
  x0 += ks2; x1 += ks0 + 2u;
#pragma unroll
  for (int i = 0; i < 4; ++i) { x0 += x1; x1 = (x1 << rA[i]) | (x1 >> (32 - rA[i])); x1 ^= x0; }
  x0 += ks0; x1 += ks1 + 3u;
#pragma unroll
  for (int i = 0; i < 4; ++i) { x0 += x1; x1 = (x1 << rB[i]) | (x1 >> (32 - rB[i])); x1 ^= x0; }
  x0 += ks1; x1 += ks2 + 4u;
#pragma unroll
  for (int i = 0; i < 4; ++i) { x0 += x1; x1 = (x1 << rA[i]) | (x1 >> (32 - rA[i])); x1 ^= x0; }
  o0 = x0 + ks2; o1 = x1 + ks0 + 5u;
}

__device__ __forceinline__ float gumbel_from_bits(uint32_t bits) {
  uint32_t fb = (bits >> 9) | 0x3f800000u;
  float u = __uint_as_float(fb) - 1.0f;
  u = fmaxf(u, 1.17549435e-38f);
  return -logf(-logf(u));
}

__device__ __forceinline__ float sigm(float x) { return 1.0f / (1.0f + __expf(-x)); }
__device__ __forceinline__ float tanh_(float x) {
  float e = __expf(2.0f * x);
  return 1.0f - 2.0f / (e + 1.0f);
}

__device__ __forceinline__ float dot64(const float* __restrict__ w, const float* h) {
  float a = 0.f;
#pragma unroll
  for (int k = 0; k < 64; ++k) a = fmaf(w[k], h[k], a);
  return a;
}

// Team-of-4 categorical sample + logprob. Lane g owns candidates c = g + 4*i.
// Padded slots carry -INF logits (z = -INF never beats a real candidate;
// all-pad lanes lose in the butterfly). Tie-break = lowest index (first max).
template <int N>
__device__ __forceinline__ void samp_team(const float* lg, int g, int C,
                                          uint32_t k0, uint32_t k1, int b,
                                          int& sOut, float& lpOut) {
  float m = -__builtin_inff();
#pragma unroll
  for (int i = 0; i < N; ++i) m = fmaxf(m, lg[i]);
  m = fmaxf(m, __shfl_xor(m, 1));
  m = fmaxf(m, __shfl_xor(m, 2));
  float se = 0.f;
#pragma unroll
  for (int i = 0; i < N; ++i) se += expf(lg[i] - m);
  se += __shfl_xor(se, 1);
  se += __shfl_xor(se, 2);
  const float lse = logf(se);
  float bz = -__builtin_inff(), bl = 0.f;
  int bi = 0x7fffffff;
#pragma unroll
  for (int i = 0; i < N; ++i) {
    const int c = g + 4 * i;
    uint32_t o0, o1; tf2x32(k0, k1, 0u, (uint32_t)(b * C + c), o0, o1);
    const float z = lg[i] + gumbel_from_bits(o0 ^ o1);
    if (z > bz || (z == bz && c < bi)) { bz = z; bi = c; bl = lg[i]; }
  }
#pragma unroll
  for (int d = 1; d <= 2; d <<= 1) {
    const float z2 = __shfl_xor(bz, d);
    const int i2 = __shfl_xor(bi, d);
    const float l2 = __shfl_xor(bl, d);
    if (z2 > bz || (z2 == bz && i2 < bi)) { bz = z2; bi = i2; bl = l2; }
  }
  sOut = bi;
  lpOut = (bl - m) - lse;
}

// ---------------- kernel A: embedW precompute + W_hh pack ----------------
// embedW[v][j] = b_ih[j] + b_hh[j] + sum_k embed[v][k]*W_ih[j][k]
// WTp[k*256 + w*32 + j] = W_hh[(g*64 + w*8 + i)*64 + k], j = g*8+i
__global__ __launch_bounds__(256) void k_prep(
    const float* __restrict__ embed, const float* __restrict__ W_ih,
    const float* __restrict__ W_hh, const float* __restrict__ b_ih,
    const float* __restrict__ b_hh, float* __restrict__ embedW,
    float* __restrict__ WTp) {
  if (blockIdx.x >= NV) {
    int idx = (blockIdx.x - NV) * 256 + threadIdx.x;  // 0..16383
    int k = idx >> 8, rem = idx & 255;
    int w = rem >> 5, j = rem & 31, gg = j >> 3, i = j & 7;
    WTp[idx] = W_hh[(gg * 64 + w * 8 + i) * 64 + k];
    return;
  }
  __shared__ float er[64];
  int v = blockIdx.x;
  if (threadIdx.x < 64) er[threadIdx.x] = embed[v * 64 + threadIdx.x];
  __syncthreads();
  int j = threadIdx.x;
  float a = b_ih[j] + b_hh[j];
#pragma unroll
  for (int k = 0; k < 64; ++k) a = fmaf(W_ih[j * 64 + k], er[k], a);
  embedW[v * 256 + j] = a;
}

// FMA 32 outputs for one k: weights from (runtime-uniform) VMEM broadcast.
#define K_FMA(WPTR, HK)                                                        \
  {                                                                            \
    const float4 a0 = *(const float4*)((WPTR) + 0);                            \
    const float4 a1 = *(const float4*)((WPTR) + 4);                            \
    const float4 a2 = *(const float4*)((WPTR) + 8);                            \
    const float4 a3 = *(const float4*)((WPTR) + 12);                           \
    const float4 a4 = *(const float4*)((WPTR) + 16);                           \
    const float4 a5 = *(const float4*)((WPTR) + 20);                           \
    const float4 a6 = *(const float4*)((WPTR) + 24);                           \
    const float4 a7 = *(const float4*)((WPTR) + 28);                           \
    acc[0]  = fmaf(a0.x, (HK), acc[0]);  acc[1]  = fmaf(a0.y, (HK), acc[1]);   \
    acc[2]  = fmaf(a0.z, (HK), acc[2]);  acc[3]  = fmaf(a0.w, (HK), acc[3]);   \
    acc[4]  = fmaf(a1.x, (HK), acc[4]);  acc[5]  = fmaf(a1.y, (HK), acc[5]);   \
    acc[6]  = fmaf(a1.z, (HK), acc[6]);  acc[7]  = fmaf(a1.w, (HK), acc[7]);   \
    acc[8]  = fmaf(a2.x, (HK), acc[8]);  acc[9]  = fmaf(a2.y, (HK), acc[9]);   \
    acc[10] = fmaf(a2.z, (HK), acc[10]); acc[11] = fmaf(a2.w, (HK), acc[11]);  \
    acc[12] = fmaf(a3.x, (HK), acc[12]); acc[13] = fmaf(a3.y, (HK), acc[13]);  \
    acc[14] = fmaf(a3.z, (HK), acc[14]); acc[15] = fmaf(a3.w, (HK), acc[15]);  \
    acc[16] = fmaf(a4.x, (HK), acc[16]); acc[17] = fmaf(a4.y, (HK), acc[17]);  \
    acc[18] = fmaf(a4.z, (HK), acc[18]); acc[19] = fmaf(a4.w, (HK), acc[19]);  \
    acc[20] = fmaf(a5.x, (HK), acc[20]); acc[21] = fmaf(a5.y, (HK), acc[21]);  \
    acc[22] = fmaf(a5.z, (HK), acc[22]); acc[23] = fmaf(a5.w, (HK), acc[23]);  \
    acc[24] = fmaf(a6.x, (HK), acc[24]); acc[25] = fmaf(a6.y, (HK), acc[25]);  \
    acc[26] = fmaf(a6.z, (HK), acc[26]); acc[27] = fmaf(a6.w, (HK), acc[27]);  \
    acc[28] = fmaf(a7.x, (HK), acc[28]); acc[29] = fmaf(a7.y, (HK), acc[29]);  \
    acc[30] = fmaf(a7.z, (HK), acc[30]); acc[31] = fmaf(a7.w, (HK), acc[31]);  \
  }

// ---------------- kernel B: LSTM ----------------
// 512 WGs x 512 threads; WG covers 64 rows (lane=row), wave w owns units [8w,8w+8).
// Weights stream through VMEM with a formally-divergent but runtime-uniform
// address (TA merges 64 identical lane addresses -> one L1 txn, broadcast fill).
// This moves weight traffic off the SGPR-capped SMEM path (round-2 stall).
__global__ __launch_bounds__(512, 4) void k_lstm(
    const int* __restrict__ inst0, const int* __restrict__ inst1,
    const float* __restrict__ embedW, const float* __restrict__ WTp,
    float* __restrict__ hT) {
  __shared__ float hb[2][64 * 64];  // 32 KB
  const int tid = threadIdx.x;
  const int lane = tid & 63;
  const int u0 = (tid >> 6) << 3;          // wave*8  (LDS/store mapping)
  const int wOff = (tid & ~63) >> 1;       // wave*32 (formally divergent -> VMEM)
  const int flat = blockIdx.x * 64 + lane;
  const int s = blockIdx.x >> 8;
  const int b = flat & (NB - 1);
  const int* __restrict__ inst = s ? inst1 : inst0;
  const float* __restrict__ Wd = WTp + wOff;

  for (int i = tid; i < 64 * 64; i += 512) hb[0][i] = 0.f;
  float c[8];
#pragma unroll
  for (int i = 0; i < 8; ++i) c[i] = 0.f;

  int vcur = inst[b * NSEQ];
  __syncthreads();

  int cur = 0;
#pragma unroll 1
  for (int t = 0; t < NSEQ; ++t) {
    const int vnext = inst[b * NSEQ + min(t + 1, NSEQ - 1)];
    // embedW row loads: issued now, consumed at epilogue (whole step to land)
    const float* er = embedW + vcur * 256 + u0;
    const float4 em0 = *(const float4*)(er + 0),   em1 = *(const float4*)(er + 4);
    const float4 em2 = *(const float4*)(er + 64),  em3 = *(const float4*)(er + 68);
    const float4 em4 = *(const float4*)(er + 128), em5 = *(const float4*)(er + 132);
    const float4 em6 = *(const float4*)(er + 192), em7 = *(const float4*)(er + 196);

    float acc[32];
#pragma unroll
    for (int j = 0; j < 32; ++j) acc[j] = 0.f;

#pragma unroll 1
    for (int bq = 0; bq < 8; ++bq) {
      float vh[8];
#pragma unroll
      for (int kk = 0; kk < 8; ++kk) vh[kk] = hb[cur][(bq * 8 + kk) * 64 + lane];
#pragma unroll
      for (int kk = 0; kk < 8; ++kk) {
        const float* w = Wd + (bq * 8 + kk) * 256;
        K_FMA(w, vh[kk]);
      }
    }

    // fold in precomputed x@W_ih + biases
    acc[0]  += em0.x; acc[1]  += em0.y; acc[2]  += em0.z; acc[3]  += em0.w;
    acc[4]  += em1.x; acc[5]  += em1.y; acc[6]  += em1.z; acc[7]  += em1.w;
    acc[8]  += em2.x; acc[9]  += em2.y; acc[10] += em2.z; acc[11] += em2.w;
    acc[12] += em3.x; acc[13] += em3.y; acc[14] += em3.z; acc[15] += em3.w;
    acc[16] += em4.x; acc[17] += em4.y; acc[18] += em4.z; acc[19] += em4.w;
    acc[20] += em5.x; acc[21] += em5.y; acc[22] += em5.z; acc[23] += em5.w;
    acc[24] += em6.x; acc[25] += em6.y; acc[26] += em6.z; acc[27] += em6.w;
    acc[28] += em7.x; acc[29] += em7.y; acc[30] += em7.z; acc[31] += em7.w;

#pragma unroll
    for (int i = 0; i < 8; ++i) {
      const float iv = acc[i], fv = acc[8 + i], gv = acc[16 + i], ov = acc[24 + i];
      const float ci = sigm(fv) * c[i] + sigm(iv) * tanh_(gv);
      c[i] = ci;
      hb[cur ^ 1][(u0 + i) * 64 + lane] = sigm(ov) * tanh_(ci);
    }
    __syncthreads();
    cur ^= 1;
    vcur = vnext;
  }
#pragma unroll
  for (int i = 0; i < 8; ++i)
    hT[(u0 + i) * NROWS + flat] = hb[cur][(u0 + i) * 64 + lane];
}

// ---------------- kernel C: heads, 4-lane team per row ----------------
// 512 WGs x 256 threads; even blocks = dialog step 0, odd = step 1.
// Lane g = tid&3 within a team; team row b = (blockIdx>>1)*64 + tid>>2.
__global__ __launch_bounds__(256) void k_heads(
    const int* __restrict__ canvas0, const int* __restrict__ canvas1,
    const int* __restrict__ ref,
    const float* __restrict__ Wc, const float* __restrict__ bc,
    const float* __restrict__ Ws, const float* __restrict__ bs,
    const float* __restrict__ Wl, const float* __restrict__ bl,
    const float* __restrict__ Wr1, const float* __restrict__ br1,
    const float* __restrict__ Wr2, const float* __restrict__ br2,
    const float* __restrict__ Wp, const float* __restrict__ bp,
    const float* __restrict__ hT, float* __restrict__ out) {
  const int tid = threadIdx.x;
  const int g = tid & 3;
  const int s = blockIdx.x & 1;
  const int b = (blockIdx.x >> 1) * 64 + (tid >> 2);
  const float NEG = -__builtin_inff();

  uint32_t kk0[7], kk1[7];
#pragma unroll
  for (int i = 0; i < 7; ++i) {
    uint32_t o0, o1; tf2x32(0u, 42u, 0u, (uint32_t)i, o0, o1);
    kk0[i] = o0; kk1[i] = o1;
  }

  float h[64];
#pragma unroll
  for (int u = 0; u < 64; ++u) h[u] = hT[u * NROWS + s * NB + b];

  // C=3 heads: lane g<3 owns candidate g (dot order identical to round 2 -> bit-exact z)
  float lgc[1], lgs[1];
  lgc[0] = (g < 3) ? (bc[g] + dot64(Wc + g * 64, h)) : NEG;
  lgs[0] = (g < 3) ? (bs[g] + dot64(Ws + g * 64, h)) : NEG;

  if (s == 0) {
    int cs0, ss0, loc0; float clp0, slp0, llp0;
    samp_team<1>(lgc, g, 3, kk0[0], kk1[0], b, cs0, clp0);
    samp_team<1>(lgs, g, 3, kk0[1], kk1[1], b, ss0, slp0);
    float lgl[7];
#pragma unroll
    for (int i = 0; i < 7; ++i) {
      const int cc = g + 4 * i;
      lgl[i] = (cc < 25) ? (bl[cc] + dot64(Wl + cc * 64, h)) : NEG;
    }
    samp_team<7>(lgl, g, 25, kk0[2], kk1[2], b, loc0, llp0);

    if (g == 0) {
      const int p0 = min(max(loc0, 0), 24);
      const int4 pt = ((const int4*)(canvas1 + b * 100))[p0];
      const bool ok0 = (loc0 >= 0) && (loc0 < 25) && (pt.x + pt.y + pt.z + pt.w >= 0);
      const float loc_r0 = ok0 ? 1.f : -1.f;
      const float col_r0 = ok0 ? ((cs0 == pt.x) ? 1.f : -1.f) : 0.f;
      out[0 * NB + b] = clp0;
      out[1 * NB + b] = slp0;
      out[2 * NB + b] = llp0;
      out[7 * NB + b] = loc_r0;
      out[8 * NB + b] = col_r0;
      out[9 * NB + b] = loc_r0;
    }
  } else {
    int cs1, ss1, ls1; float clp1, slp1, llp1;
    samp_team<1>(lgc, g, 3, kk0[3], kk1[3], b, cs1, clp1);
    samp_team<1>(lgs, g, 3, kk0[4], kk1[4], b, ss1, slp1);
    float lgp[2];
#pragma unroll
    for (int i = 0; i < 2; ++i) {
      const int cc = g + 4 * i;
      lgp[i] = bp[cc] + dot64(Wp + cc * 64, h);
    }
    samp_team<2>(lgp, g, 8, kk0[5], kk1[5], b, ls1, llp1);

    // attention MLP: lane g owns hidden units j = g+4i (relu stays per-j exact)
    float uv8[8], w64[8], w65[8], w66[8], w67[8], wr2[8];
#pragma unroll
    for (int i = 0; i < 8; ++i) {
      const int j = g + 4 * i;
      uv8[i] = br1[j] + dot64(Wr1 + j * 68, h);
      const float* wr = Wr1 + j * 68 + 64;
      w64[i] = wr[0]; w65[i] = wr[1]; w66[i] = wr[2]; w67[i] = wr[3];
      wr2[i] = Wr2[j];
    }
    float lgA[7];
#pragma unroll
    for (int i = 0; i < 7; ++i) lgA[i] = NEG;
    const float b2 = br2[0];
#pragma unroll
    for (int p = 0; p < 25; ++p) {
      const int4 c4 = ((const int4*)(canvas0 + b * 100))[p];
      const float f0 = (float)c4.x, f1 = (float)c4.y;
      const float f2 = (float)c4.z, f3 = (float)c4.w;
      float part = 0.f;
#pragma unroll
      for (int i = 0; i < 8; ++i) {
        float hj = uv8[i];
        hj = fmaf(w64[i], f0, hj);
        hj = fmaf(w65[i], f1, hj);
        hj = fmaf(w66[i], f2, hj);
        hj = fmaf(w67[i], f3, hj);
        part = fmaf(wr2[i], fmaxf(hj, 0.f), part);
      }
      part += __shfl_xor(part, 1);
      part += __shfl_xor(part, 2);
      const float ap = b2 + part;
      if ((p & 3) == g) lgA[p >> 2] = ap;
    }
    int att_s; float alp1;
    samp_team<7>(lgA, g, 25, kk0[6], kk1[6], b, att_s, alp1);

    if (g == 0) {
      const int4 r4 = ((const int4*)(canvas0 + b * 100))[att_s];
      const int4 rr = *(const int4*)(ref + b * 4);
      const bool match = (r4.x == rr.x) && (r4.y == rr.y) &&
                         (r4.z == rr.z) && (r4.w == rr.w);
      const float att_reward = match ? 1.f : -1.f;
      const int ox = (int)((0x22001120u >> (ls1 * 4)) & 0xFu) - 1;
      const int oy = (int)((0x20200211u >> (ls1 * 4)) & 0xFu) - 1;
      const int loc1 = (r4.z + ox) * 5 + (r4.w + oy);
      const int p1 = min(max(loc1, 0), 24);
      const int4 q4 = ((const int4*)(canvas1 + b * 100))[p1];
      const bool ok1 = (loc1 >= 0) && (loc1 < 25) && (q4.x + q4.y + q4.z + q4.w >= 0);
      const float loc_r1 = ok1 ? 1.f : -1.f;
      const float col_r1 = ok1 ? ((cs1 == q4.x) ? 1.f : -1.f) : 0.f;
      out[3 * NB + b]  = clp1;
      out[4 * NB + b]  = slp1;
      out[5 * NB + b]  = llp1;
      out[6 * NB + b]  = alp1;
      out[10 * NB + b] = loc_r1;
      out[11 * NB + b] = col_r1;
      out[12 * NB + b] = loc_r1;
      out[13 * NB + b] = att_reward;
    }
  }
}

extern "C" void kernel_launch(void* const* d_in, const int* in_sizes, int n_in,
                              void* d_out, int out_size, void* d_ws, size_t ws_size,
                              hipStream_t stream) {
  const int* inst0 = (const int*)d_in[0];
  const int* inst1 = (const int*)d_in[1];
  const int* canvas0 = (const int*)d_in[2];
  const int* canvas1 = (const int*)d_in[3];
  const int* ref = (const int*)d_in[4];
  const float* embed = (const float*)d_in[5];
  const float* W_ih = (const float*)d_in[6];
  const float* W_hh = (const float*)d_in[7];
  const float* b_ih = (const float*)d_in[8];
  const float* b_hh = (const float*)d_in[9];
  const float* Wc = (const float*)d_in[10];
  const float* bc = (const float*)d_in[11];
  const float* Ws = (const float*)d_in[12];
  const float* bs = (const float*)d_in[13];
  const float* Wl = (const float*)d_in[14];
  const float* bl = (const float*)d_in[15];
  const float* Wr1 = (const float*)d_in[16];
  const float* br1 = (const float*)d_in[17];
  const float* Wr2 = (const float*)d_in[18];
  const float* br2 = (const float*)d_in[19];
  const float* Wp = (const float*)d_in[20];
  const float* bp = (const float*)d_in[21];

  float* ws = (float*)d_ws;
  float* embedW = ws;                    // 1001*256
  float* WTp = embedW + NV * 256;        // 64*256 packed
  float* hT = WTp + 64 * 256;            // 64*32768
  float* out = (float*)d_out;

  k_prep<<<NV + 64, 256, 0, stream>>>(embed, W_ih, W_hh, b_ih, b_hh, embedW, WTp);
  k_lstm<<<512, 512, 0, stream>>>(inst0, inst1, embedW, WTp, hT);
  k_heads<<<512, 256, 0, stream>>>(canvas0, canvas1, ref, Wc, bc, Ws, bs,
                                   Wl, bl, Wr1, br1, Wr2, br2, Wp, bp, hT, out);
}

// Round 4
// 796.165 us; speedup vs baseline: 2.8946x; 2.8946x over previous
//
#include <hip/hip_runtime.h>
#include <stdint.h>
#include <math.h>

#define NB 16384      // batch
#define NSEQ 32       // sequence length
#define NV 1001       // vocab (V+1)
#define NROWS 32768   // 2 * NB flattened rows

// ---------------- threefry2x32 (JAX-exact) ----------------
__device__ __forceinline__ void tf2x32(uint32_t k0, uint32_t k1,
                                       uint32_t x0, uint32_t x1,
                                       uint32_t& o0, uint32_t& o1) {
  const uint32_t ks0 = k0, ks1 = k1, ks2 = k0 ^ k1 ^ 0x1BD11BDAu;
  x0 += ks0; x1 += ks1;
  const int rA[4] = {13, 15, 26, 6};
  const int rB[4] = {17, 29, 16, 24};
#pragma unroll
  for (int i = 0; i < 4; ++i) { x0 += x1; x1 = (x1 << rA[i]) | (x1 >> (32 - rA[i])); x1 ^= x0; }
  x0 += ks1; x1 += ks2 + 1u;
#pragma unroll
  for (int i = 0; i < 4; ++i) { x0 += x1; x1 = (x1 << rB[i]) | (x1 >> (32 - rB[i])); x1 ^= x0; }
  x0 += ks2; x1 += ks0 + 2u;
#pragma unroll
  for (int i = 0; i < 4; ++i) { x0 += x1; x1 = (x1 << rA[i]) | (x1 >> (32 - rA[i])); x1 ^= x0; }
  x0 += ks0; x1 += ks1 + 3u;
#pragma unroll
  for (int i = 0; i < 4; ++i) { x0 += x1; x1 = (x1 << rB[i]) | (x1 >> (32 - rB[i])); x1 ^= x0; }
  x0 += ks1; x1 += ks2 + 4u;
#pragma unroll
  for (int i = 0; i < 4; ++i) { x0 += x1; x1 = (x1 << rA[i]) | (x1 >> (32 - rA[i])); x1 ^= x0; }
  o0 = x0 + ks2; o1 = x1 + ks0 + 5u;
}

__device__ __forceinline__ float gumbel_from_bits(uint32_t bits) {
  uint32_t fb = (bits >> 9) | 0x3f800000u;
  float u = __uint_as_float(fb) - 1.0f;
  u = fmaxf(u, 1.17549435e-38f);
  return -logf(-logf(u));
}

__device__ __forceinline__ float sigm(float x) { return 1.0f / (1.0f + __expf(-x)); }
__device__ __forceinline__ float tanh_(float x) {
  float e = __expf(2.0f * x);
  return 1.0f - 2.0f / (e + 1.0f);
}

__device__ __forceinline__ float dot64(const float* __restrict__ w, const float* h) {
  float a = 0.f;
#pragma unroll
  for (int k = 0; k < 64; ++k) a = fmaf(w[k], h[k], a);
  return a;
}

// Team-of-4 categorical sample + logprob. Lane g owns candidates c = g + 4*i.
template <int N>
__device__ __forceinline__ void samp_team(const float* lg, int g, int C,
                                          uint32_t k0, uint32_t k1, int b,
                                          int& sOut, float& lpOut) {
  float m = -__builtin_inff();
#pragma unroll
  for (int i = 0; i < N; ++i) m = fmaxf(m, lg[i]);
  m = fmaxf(m, __shfl_xor(m, 1));
  m = fmaxf(m, __shfl_xor(m, 2));
  float se = 0.f;
#pragma unroll
  for (int i = 0; i < N; ++i) se += expf(lg[i] - m);
  se += __shfl_xor(se, 1);
  se += __shfl_xor(se, 2);
  const float lse = logf(se);
  float bz = -__builtin_inff(), bl = 0.f;
  int bi = 0x7fffffff;
#pragma unroll
  for (int i = 0; i < N; ++i) {
    const int c = g + 4 * i;
    uint32_t o0, o1; tf2x32(k0, k1, 0u, (uint32_t)(b * C + c), o0, o1);
    const float z = lg[i] + gumbel_from_bits(o0 ^ o1);
    if (z > bz || (z == bz && c < bi)) { bz = z; bi = c; bl = lg[i]; }
  }
#pragma unroll
  for (int d = 1; d <= 2; d <<= 1) {
    const float z2 = __shfl_xor(bz, d);
    const int i2 = __shfl_xor(bi, d);
    const float l2 = __shfl_xor(bl, d);
    if (z2 > bz || (z2 == bz && i2 < bi)) { bz = z2; bi = i2; bl = l2; }
  }
  sOut = bi;
  lpOut = (bl - m) - lse;
}

// ---------------- kernel A: embedW precompute + W_hh pack ----------------
// embedW[v][j] = b_ih[j] + b_hh[j] + sum_k embed[v][k]*W_ih[j][k]
// WTp[k*256 + w*32 + g*8 + i] = W_hh[(g*64 + w*8 + i)*64 + k]
__global__ __launch_bounds__(256) void k_prep(
    const float* __restrict__ embed, const float* __restrict__ W_ih,
    const float* __restrict__ W_hh, const float* __restrict__ b_ih,
    const float* __restrict__ b_hh, float* __restrict__ embedW,
    float* __restrict__ WTp) {
  if (blockIdx.x >= NV) {
    int idx = (blockIdx.x - NV) * 256 + threadIdx.x;  // 0..16383
    int k = idx >> 8, rem = idx & 255;
    int w = rem >> 5, j = rem & 31, gg = j >> 3, i = j & 7;
    WTp[idx] = W_hh[(gg * 64 + w * 8 + i) * 64 + k];
    return;
  }
  __shared__ float er[64];
  int v = blockIdx.x;
  if (threadIdx.x < 64) er[threadIdx.x] = embed[v * 64 + threadIdx.x];
  __syncthreads();
  int j = threadIdx.x;
  float a = b_ih[j] + b_hh[j];
#pragma unroll
  for (int k = 0; k < 64; ++k) a = fmaf(W_ih[j * 64 + k], er[k], a);
  embedW[v * 256 + j] = a;
}

// One k-step: 8 uniform b128 weight reads from LDS, 32 j x 2 rows FMA.
#define K_FMA2(WPTR, HK0, HK1)                                                  \
  {                                                                             \
    const float4 w0 = *(const float4*)((WPTR) + 0);                             \
    const float4 w1 = *(const float4*)((WPTR) + 4);                             \
    const float4 w2 = *(const float4*)((WPTR) + 8);                             \
    const float4 w3 = *(const float4*)((WPTR) + 12);                            \
    const float4 w4 = *(const float4*)((WPTR) + 16);                            \
    const float4 w5 = *(const float4*)((WPTR) + 20);                            \
    const float4 w6 = *(const float4*)((WPTR) + 24);                            \
    const float4 w7 = *(const float4*)((WPTR) + 28);                            \
    acc0[0]  = fmaf(w0.x, (HK0), acc0[0]);  acc1[0]  = fmaf(w0.x, (HK1), acc1[0]);  \
    acc0[1]  = fmaf(w0.y, (HK0), acc0[1]);  acc1[1]  = fmaf(w0.y, (HK1), acc1[1]);  \
    acc0[2]  = fmaf(w0.z, (HK0), acc0[2]);  acc1[2]  = fmaf(w0.z, (HK1), acc1[2]);  \
    acc0[3]  = fmaf(w0.w, (HK0), acc0[3]);  acc1[3]  = fmaf(w0.w, (HK1), acc1[3]);  \
    acc0[4]  = fmaf(w1.x, (HK0), acc0[4]);  acc1[4]  = fmaf(w1.x, (HK1), acc1[4]);  \
    acc0[5]  = fmaf(w1.y, (HK0), acc0[5]);  acc1[5]  = fmaf(w1.y, (HK1), acc1[5]);  \
    acc0[6]  = fmaf(w1.z, (HK0), acc0[6]);  acc1[6]  = fmaf(w1.z, (HK1), acc1[6]);  \
    acc0[7]  = fmaf(w1.w, (HK0), acc0[7]);  acc1[7]  = fmaf(w1.w, (HK1), acc1[7]);  \
    acc0[8]  = fmaf(w2.x, (HK0), acc0[8]);  acc1[8]  = fmaf(w2.x, (HK1), acc1[8]);  \
    acc0[9]  = fmaf(w2.y, (HK0), acc0[9]);  acc1[9]  = fmaf(w2.y, (HK1), acc1[9]);  \
    acc0[10] = fmaf(w2.z, (HK0), acc0[10]); acc1[10] = fmaf(w2.z, (HK1), acc1[10]); \
    acc0[11] = fmaf(w2.w, (HK0), acc0[11]); acc1[11] = fmaf(w2.w, (HK1), acc1[11]); \
    acc0[12] = fmaf(w3.x, (HK0), acc0[12]); acc1[12] = fmaf(w3.x, (HK1), acc1[12]); \
    acc0[13] = fmaf(w3.y, (HK0), acc0[13]); acc1[13] = fmaf(w3.y, (HK1), acc1[13]); \
    acc0[14] = fmaf(w3.z, (HK0), acc0[14]); acc1[14] = fmaf(w3.z, (HK1), acc1[14]); \
    acc0[15] = fmaf(w3.w, (HK0), acc0[15]); acc1[15] = fmaf(w3.w, (HK1), acc1[15]); \
    acc0[16] = fmaf(w4.x, (HK0), acc0[16]); acc1[16] = fmaf(w4.x, (HK1), acc1[16]); \
    acc0[17] = fmaf(w4.y, (HK0), acc0[17]); acc1[17] = fmaf(w4.y, (HK1), acc1[17]); \
    acc0[18] = fmaf(w4.z, (HK0), acc0[18]); acc1[18] = fmaf(w4.z, (HK1), acc1[18]); \
    acc0[19] = fmaf(w4.w, (HK0), acc0[19]); acc1[19] = fmaf(w4.w, (HK1), acc1[19]); \
    acc0[20] = fmaf(w5.x, (HK0), acc0[20]); acc1[20] = fmaf(w5.x, (HK1), acc1[20]); \
    acc0[21] = fmaf(w5.y, (HK0), acc0[21]); acc1[21] = fmaf(w5.y, (HK1), acc1[21]); \
    acc0[22] = fmaf(w5.z, (HK0), acc0[22]); acc1[22] = fmaf(w5.z, (HK1), acc1[22]); \
    acc0[23] = fmaf(w5.w, (HK0), acc0[23]); acc1[23] = fmaf(w5.w, (HK1), acc1[23]); \
    acc0[24] = fmaf(w6.x, (HK0), acc0[24]); acc1[24] = fmaf(w6.x, (HK1), acc1[24]); \
    acc0[25] = fmaf(w6.y, (HK0), acc0[25]); acc1[25] = fmaf(w6.y, (HK1), acc1[25]); \
    acc0[26] = fmaf(w6.z, (HK0), acc0[26]); acc1[26] = fmaf(w6.z, (HK1), acc1[26]); \
    acc0[27] = fmaf(w6.w, (HK0), acc0[27]); acc1[27] = fmaf(w6.w, (HK1), acc1[27]); \
    acc0[28] = fmaf(w7.x, (HK0), acc0[28]); acc1[28] = fmaf(w7.x, (HK1), acc1[28]); \
    acc0[29] = fmaf(w7.y, (HK0), acc0[29]); acc1[29] = fmaf(w7.y, (HK1), acc1[29]); \
    acc0[30] = fmaf(w7.z, (HK0), acc0[30]); acc1[30] = fmaf(w7.z, (HK1), acc1[30]); \
    acc0[31] = fmaf(w7.w, (HK0), acc0[31]); acc1[31] = fmaf(w7.w, (HK1), acc1[31]); \
  }

// ---------------- kernel B: LSTM ----------------
// 256 WGs x 512 threads = 1 WG/CU. WG covers 128 rows; lane covers rows
// (lane, lane+64). Wave w owns units [8w,8w+8) -> 64 accumulators.
// W_hh staged in LDS ONCE (step-invariant, 64 KB); per-k weight reads are
// wave-uniform ds_read_b128 broadcasts (conflict-free). h double-buffered in
// LDS (64 KB) -> 1 barrier/step. launch_bounds(512,2) = 256-VGPR budget (no
// spill; round-3 spill was the (512,4) 128-cap).
__global__ __launch_bounds__(512, 2) void k_lstm(
    const int* __restrict__ inst0, const int* __restrict__ inst1,
    const float* __restrict__ embedW, const float* __restrict__ WTp,
    float* __restrict__ hT) {
  extern __shared__ float smem[];
  float* Wlds = smem;           // [64 k][256 j]  64 KB
  float* hbuf = smem + 16384;   // [2][64 k][128 row]  64 KB

  const int tid = threadIdx.x;
  const int lane = tid & 63;
  const int wave = tid >> 6;          // 0..7
  const int u0 = wave * 8;
  const int jbase = wave * 32;
  const int blk = blockIdx.x;         // 0..255
  const int r0 = blk * 128 + lane;    // rows r0, r0+64
  const int s = blk >> 7;
  const int b0 = r0 & (NB - 1);
  const int b1 = (r0 + 64) & (NB - 1);
  const int* __restrict__ inst = s ? inst1 : inst0;

  // stage weights (once) and zero h buffer 0
  for (int i = tid; i < 4096; i += 512)
    ((float4*)Wlds)[i] = ((const float4*)WTp)[i];
  for (int i = tid; i < 8192; i += 512) hbuf[i] = 0.f;

  float c0[8], c1[8];
#pragma unroll
  for (int i = 0; i < 8; ++i) { c0[i] = 0.f; c1[i] = 0.f; }

  int v0 = inst[b0 * NSEQ];
  int v1 = inst[b1 * NSEQ];
  __syncthreads();

  int cur = 0;
#pragma unroll 1
  for (int t = 0; t < NSEQ; ++t) {
    // acc init = embedW rows (x@W_ih + biases), global loads (L2-hot)
    float acc0[32], acc1[32];
    {
      const float* e0 = embedW + v0 * 256 + u0;
      const float* e1 = embedW + v1 * 256 + u0;
#pragma unroll
      for (int gg = 0; gg < 4; ++gg) {
        const float4 a0 = *(const float4*)(e0 + gg * 64);
        const float4 a1 = *(const float4*)(e0 + gg * 64 + 4);
        const float4 b0v = *(const float4*)(e1 + gg * 64);
        const float4 b1v = *(const float4*)(e1 + gg * 64 + 4);
        acc0[gg * 8 + 0] = a0.x;  acc0[gg * 8 + 1] = a0.y;
        acc0[gg * 8 + 2] = a0.z;  acc0[gg * 8 + 3] = a0.w;
        acc0[gg * 8 + 4] = a1.x;  acc0[gg * 8 + 5] = a1.y;
        acc0[gg * 8 + 6] = a1.z;  acc0[gg * 8 + 7] = a1.w;
        acc1[gg * 8 + 0] = b0v.x; acc1[gg * 8 + 1] = b0v.y;
        acc1[gg * 8 + 2] = b0v.z; acc1[gg * 8 + 3] = b0v.w;
        acc1[gg * 8 + 4] = b1v.x; acc1[gg * 8 + 5] = b1v.y;
        acc1[gg * 8 + 6] = b1v.z; acc1[gg * 8 + 7] = b1v.w;
      }
    }
    // prefetch next vocab ids
    const int tn = min(t + 1, NSEQ - 1);
    const int v0n = inst[b0 * NSEQ + tn];
    const int v1n = inst[b1 * NSEQ + tn];

    const float* __restrict__ hc = hbuf + cur * 8192;
    const float* __restrict__ Wb = Wlds + jbase;
#pragma unroll 1
    for (int bq = 0; bq < 8; ++bq) {
      float h0[8], h1[8];
#pragma unroll
      for (int kk = 0; kk < 8; ++kk) {
        h0[kk] = hc[(bq * 8 + kk) * 128 + lane];
        h1[kk] = hc[(bq * 8 + kk) * 128 + 64 + lane];
      }
#pragma unroll
      for (int kk = 0; kk < 8; ++kk) {
        const float* w = Wb + (bq * 8 + kk) * 256;
        K_FMA2(w, h0[kk], h1[kk]);
      }
    }

    float* __restrict__ hn = hbuf + (cur ^ 1) * 8192;
#pragma unroll
    for (int i = 0; i < 8; ++i) {
      const float iv0 = acc0[i], fv0 = acc0[8 + i], gv0 = acc0[16 + i], ov0 = acc0[24 + i];
      const float ci0 = sigm(fv0) * c0[i] + sigm(iv0) * tanh_(gv0);
      c0[i] = ci0;
      hn[(u0 + i) * 128 + lane] = sigm(ov0) * tanh_(ci0);
      const float iv1 = acc1[i], fv1 = acc1[8 + i], gv1 = acc1[16 + i], ov1 = acc1[24 + i];
      const float ci1 = sigm(fv1) * c1[i] + sigm(iv1) * tanh_(gv1);
      c1[i] = ci1;
      hn[(u0 + i) * 128 + 64 + lane] = sigm(ov1) * tanh_(ci1);
    }
    __syncthreads();
    cur ^= 1;
    v0 = v0n; v1 = v1n;
  }

  const float* __restrict__ hf = hbuf + cur * 8192;
#pragma unroll
  for (int i = 0; i < 8; ++i) {
    hT[(u0 + i) * NROWS + blk * 128 + lane]      = hf[(u0 + i) * 128 + lane];
    hT[(u0 + i) * NROWS + blk * 128 + 64 + lane] = hf[(u0 + i) * 128 + 64 + lane];
  }
}

// ---------------- kernel C: heads, 4-lane team per row (bit-exact r3) ------
__global__ __launch_bounds__(256) void k_heads(
    const int* __restrict__ canvas0, const int* __restrict__ canvas1,
    const int* __restrict__ ref,
    const float* __restrict__ Wc, const float* __restrict__ bc,
    const float* __restrict__ Ws, const float* __restrict__ bs,
    const float* __restrict__ Wl, const float* __restrict__ bl,
    const float* __restrict__ Wr1, const float* __restrict__ br1,
    const float* __restrict__ Wr2, const float* __restrict__ br2,
    const float* __restrict__ Wp, const float* __restrict__ bp,
    const float* __restrict__ hT, float* __restrict__ out) {
  const int tid = threadIdx.x;
  const int g = tid & 3;
  const int s = blockIdx.x & 1;
  const int b = (blockIdx.x >> 1) * 64 + (tid >> 2);
  const float NEG = -__builtin_inff();

  uint32_t kk0[7], kk1[7];
#pragma unroll
  for (int i = 0; i < 7; ++i) {
    uint32_t o0, o1; tf2x32(0u, 42u, 0u, (uint32_t)i, o0, o1);
    kk0[i] = o0; kk1[i] = o1;
  }

  float h[64];
#pragma unroll
  for (int u = 0; u < 64; ++u) h[u] = hT[u * NROWS + s * NB + b];

  float lgc[1], lgs[1];
  lgc[0] = (g < 3) ? (bc[g] + dot64(Wc + g * 64, h)) : NEG;
  lgs[0] = (g < 3) ? (bs[g] + dot64(Ws + g * 64, h)) : NEG;

  if (s == 0) {
    int cs0, ss0, loc0; float clp0, slp0, llp0;
    samp_team<1>(lgc, g, 3, kk0[0], kk1[0], b, cs0, clp0);
    samp_team<1>(lgs, g, 3, kk0[1], kk1[1], b, ss0, slp0);
    float lgl[7];
#pragma unroll
    for (int i = 0; i < 7; ++i) {
      const int cc = g + 4 * i;
      lgl[i] = (cc < 25) ? (bl[cc] + dot64(Wl + cc * 64, h)) : NEG;
    }
    samp_team<7>(lgl, g, 25, kk0[2], kk1[2], b, loc0, llp0);

    if (g == 0) {
      const int p0 = min(max(loc0, 0), 24);
      const int4 pt = ((const int4*)(canvas1 + b * 100))[p0];
      const bool ok0 = (loc0 >= 0) && (loc0 < 25) && (pt.x + pt.y + pt.z + pt.w >= 0);
      const float loc_r0 = ok0 ? 1.f : -1.f;
      const float col_r0 = ok0 ? ((cs0 == pt.x) ? 1.f : -1.f) : 0.f;
      out[0 * NB + b] = clp0;
      out[1 * NB + b] = slp0;
      out[2 * NB + b] = llp0;
      out[7 * NB + b] = loc_r0;
      out[8 * NB + b] = col_r0;
      out[9 * NB + b] = loc_r0;
    }
  } else {
    int cs1, ss1, ls1; float clp1, slp1, llp1;
    samp_team<1>(lgc, g, 3, kk0[3], kk1[3], b, cs1, clp1);
    samp_team<1>(lgs, g, 3, kk0[4], kk1[4], b, ss1, slp1);
    float lgp[2];
#pragma unroll
    for (int i = 0; i < 2; ++i) {
      const int cc = g + 4 * i;
      lgp[i] = bp[cc] + dot64(Wp + cc * 64, h);
    }
    samp_team<2>(lgp, g, 8, kk0[5], kk1[5], b, ls1, llp1);

    float uv8[8], w64[8], w65[8], w66[8], w67[8], wr2[8];
#pragma unroll
    for (int i = 0; i < 8; ++i) {
      const int j = g + 4 * i;
      uv8[i] = br1[j] + dot64(Wr1 + j * 68, h);
      const float* wr = Wr1 + j * 68 + 64;
      w64[i] = wr[0]; w65[i] = wr[1]; w66[i] = wr[2]; w67[i] = wr[3];
      wr2[i] = Wr2[j];
    }
    float lgA[7];
#pragma unroll
    for (int i = 0; i < 7; ++i) lgA[i] = NEG;
    const float b2 = br2[0];
#pragma unroll
    for (int p = 0; p < 25; ++p) {
      const int4 c4 = ((const int4*)(canvas0 + b * 100))[p];
      const float f0 = (float)c4.x, f1 = (float)c4.y;
      const float f2 = (float)c4.z, f3 = (float)c4.w;
      float part = 0.f;
#pragma unroll
      for (int i = 0; i < 8; ++i) {
        float hj = uv8[i];
        hj = fmaf(w64[i], f0, hj);
        hj = fmaf(w65[i], f1, hj);
        hj = fmaf(w66[i], f2, hj);
        hj = fmaf(w67[i], f3, hj);
        part = fmaf(wr2[i], fmaxf(hj, 0.f), part);
      }
      part += __shfl_xor(part, 1);
      part += __shfl_xor(part, 2);
      const float ap = b2 + part;
      if ((p & 3) == g) lgA[p >> 2] = ap;
    }
    int att_s; float alp1;
    samp_team<7>(lgA, g, 25, kk0[6], kk1[6], b, att_s, alp1);

    if (g == 0) {
      const int4 r4 = ((const int4*)(canvas0 + b * 100))[att_s];
      const int4 rr = *(const int4*)(ref + b * 4);
      const bool match = (r4.x == rr.x) && (r4.y == rr.y) &&
                         (r4.z == rr.z) && (r4.w == rr.w);
      const float att_reward = match ? 1.f : -1.f;
      const int ox = (int)((0x22001120u >> (ls1 * 4)) & 0xFu) - 1;
      const int oy = (int)((0x20200211u >> (ls1 * 4)) & 0xFu) - 1;
      const int loc1 = (r4.z + ox) * 5 + (r4.w + oy);
      const int p1 = min(max(loc1, 0), 24);
      const int4 q4 = ((const int4*)(canvas1 + b * 100))[p1];
      const bool ok1 = (loc1 >= 0) && (loc1 < 25) && (q4.x + q4.y + q4.z + q4.w >= 0);
      const float loc_r1 = ok1 ? 1.f : -1.f;
      const float col_r1 = ok1 ? ((cs1 == q4.x) ? 1.f : -1.f) : 0.f;
      out[3 * NB + b]  = clp1;
      out[4 * NB + b]  = slp1;
      out[5 * NB + b]  = llp1;
      out[6 * NB + b]  = alp1;
      out[10 * NB + b] = loc_r1;
      out[11 * NB + b] = col_r1;
      out[12 * NB + b] = loc_r1;
      out[13 * NB + b] = att_reward;
    }
  }
}

extern "C" void kernel_launch(void* const* d_in, const int* in_sizes, int n_in,
                              void* d_out, int out_size, void* d_ws, size_t ws_size,
                              hipStream_t stream) {
  const int* inst0 = (const int*)d_in[0];
  const int* inst1 = (const int*)d_in[1];
  const int* canvas0 = (const int*)d_in[2];
  const int* canvas1 = (const int*)d_in[3];
  const int* ref = (const int*)d_in[4];
  const float* embed = (const float*)d_in[5];
  const float* W_ih = (const float*)d_in[6];
  const float* W_hh = (const float*)d_in[7];
  const float* b_ih = (const float*)d_in[8];
  const float* b_hh = (const float*)d_in[9];
  const float* Wc = (const float*)d_in[10];
  const float* bc = (const float*)d_in[11];
  const float* Ws = (const float*)d_in[12];
  const float* bs = (const float*)d_in[13];
  const float* Wl = (const float*)d_in[14];
  const float* bl = (const float*)d_in[15];
  const float* Wr1 = (const float*)d_in[16];
  const float* br1 = (const float*)d_in[17];
  const float* Wr2 = (const float*)d_in[18];
  const float* br2 = (const float*)d_in[19];
  const float* Wp = (const float*)d_in[20];
  const float* bp = (const float*)d_in[21];

  float* ws = (float*)d_ws;
  float* embedW = ws;                    // 1001*256
  float* WTp = embedW + NV * 256;        // 64*256 packed
  float* hT = WTp + 64 * 256;            // 64*32768
  float* out = (float*)d_out;

  k_prep<<<NV + 64, 256, 0, stream>>>(embed, W_ih, W_hh, b_ih, b_hh, embedW, WTp);
  k_lstm<<<256, 512, 131072, stream>>>(inst0, inst1, embedW, WTp, hT);
  k_heads<<<512, 256, 0, stream>>>(canvas0, canvas1, ref, Wc, bc, Ws, bs,
                                   Wl, bl, Wr1, br1, Wr2, br2, Wp, bp, hT, out);
}